// Round 1
// baseline (189.392 us; speedup 1.0000x reference)
//
#include <hip/hip_runtime.h>
#include <math.h>

#define BATCH 16384
#define NSETS 1024
#define ALPHA 0.001f
#define BETA  0.001f

// fp8 MFMA GEMM tile: 128x128 block, BK=128, 256 threads (4 waves, 2x2 wave
// grid, each wave 64x64 = 4x4 grid of 16x16x32 fp8 MFMA tiles).
// R11 restructure: exact fp32 rowsums (ms) moved OUT of the GEMM kernel into
// the BCE pass, where clipped p is already in registers:
//   rowsum_b = p_clip[b,:] . colsum(M)   (exact fp32, zero extra traffic)
// colsum(M) is finalized BEFORE the BCE pass by a tiny moebius kernel +
// 16-block write-once reduction (no memset, no cross-launch state -> safe
// under workspace re-poisoning). The GEMM kernel now does ONLY the fp8 GEMM
// for mr plus a one-atomic epilogue, eliminating the device-wide second read
// of fp32 pred (67 MB), the c_part fold, 131K rowsum atomics, and the
// stripe-last protocol.
#define BM 128
#define BN 128
#define BK 128
#define NSTRIPE (BATCH / BM)            // 128 m-stripes
#define NBLK_N  (NSETS / BN)            // 8 n-blocks per stripe
#define GEMM_BLOCKS (NSTRIPE * NBLK_N)  // 1024
#define KITER (NSETS / BK)              // 8

typedef __attribute__((ext_vector_type(4))) float f32x4;
typedef __attribute__((ext_vector_type(2))) long s64x2;

// ws float-index layout:
//   [0] mr_sum  [1] global counter (uint)  [2] ms_sum  [3] bce_sum
//       (all four zeroed by colsum_reduce_kernel, which runs before any use)
//   [16 .. 16+1024)         colsum(M), write-once by colsum_reduce_kernel
//   [2048 .. 2048+65536)    c_part[64][1024] moebius colsum partials (w-once)
// ws byte layout:
//   [393216 ..)              pred_fp8 (16.8 MB, k-interleaved)
//   [393216 + 16777216 ..)   moeb_fp8 (1 MB, k-interleaved)
#define COLSUM_OFF 16
#define CPART_OFF  2048
#define WS_PREDF8_OFF 393216
#define WS_MOEBF8_OFF (393216 + BATCH * NSETS)

__device__ __forceinline__ void gld16(const void* g, void* l) {
    __builtin_amdgcn_global_load_lds(
        (const __attribute__((address_space(1))) unsigned int*)g,
        (__attribute__((address_space(3))) unsigned int*)l, 16, 0, 0);
}

// 4 fp32 -> 4 fp8 e4m3 (OCP) packed in an int, HW converter
__device__ __forceinline__ int pk_fp8x4(float a, float b, float c, float d) {
    int v = 0;
    v = __builtin_amdgcn_cvt_pk_fp8_f32(a, b, v, 0);   // low word
    v = __builtin_amdgcn_cvt_pk_fp8_f32(c, d, v, 1);   // high word
    return v;
}

// dword-in-row permutation implementing the 8B k-chunk interleave within each
// 128B k-group: chunk o -> (o&8) | ((o&3)<<1) | ((o>>2)&1).  With this layout
// a lane's MFMA chunks (8H+q, 8H+q+4) are ADJACENT -> b128 fragment reads.
__device__ __forceinline__ int permute_dword(int d) {
    const int g = d >> 5;          // 128B group (32 dwords)
    const int w = d & 31;
    const int o = w >> 1;          // 8B chunk 0..15
    const int p = w & 1;
    const int n = (o & 8) | ((o & 3) << 1) | ((o >> 2) & 1);
    return (g << 5) | (n << 1) | p;
}

// relaxed agent-scope load: bypasses (possibly stale) L1/L2, no cache inval
__device__ __forceinline__ float coh_load(const float* p) {
    return __hip_atomic_load(p, __ATOMIC_RELAXED, __HIP_MEMORY_SCOPE_AGENT);
}

__device__ __forceinline__ float block_reduce_sum(float v, float* sm) {
    #pragma unroll
    for (int off = 32; off > 0; off >>= 1) v += __shfl_down(v, off, 64);
    const int lane = threadIdx.x & 63;
    const int wid  = threadIdx.x >> 6;
    if (lane == 0) sm[wid] = v;
    __syncthreads();
    const int nw = blockDim.x >> 6;
    v = (threadIdx.x < nw) ? sm[threadIdx.x] : 0.0f;
    if (wid == 0) {
        #pragma unroll
        for (int off = 32; off > 0; off >>= 1) v += __shfl_down(v, off, 64);
    }
    return v;  // valid in thread 0
}

// -------- k0: moebius -> fp8 (k-interleaved) + write-once colsum partials.
// Block j handles rows j*16 .. j*16+15; thread covers float4-column tid.
__global__ __launch_bounds__(256)
void moeb_convert_kernel(const float* __restrict__ moeb,
                         float*       __restrict__ ws,
                         int*         __restrict__ moeb_f8) {
    const int tid  = threadIdx.x;
    const int j    = blockIdx.x;           // 0..63
    const int base = j * 4096 + tid;
    float4 csum = make_float4(0.f, 0.f, 0.f, 0.f);
    #pragma unroll
    for (int k = 0; k < 16; k++) {
        const int i = base + k * 256;      // row j*16+k, col4 = tid
        const float4 v = ((const float4*)moeb)[i];
        const int row = i >> 8;
        moeb_f8[(row << 8) | permute_dword(i & 255)] =
            pk_fp8x4(v.x, v.y, v.z, v.w);
        csum.x += v.x; csum.y += v.y; csum.z += v.z; csum.w += v.w;
    }
    ((float4*)(ws + CPART_OFF))[j * 256 + tid] = csum;  // write-once
}

// -------- k1: reduce c_part[64][1024] -> colsum[1024] (write-once, exact,
// deterministic) and zero the four scalar accumulators for this launch.
__global__ __launch_bounds__(256)
void colsum_reduce_kernel(float* __restrict__ ws) {
    __shared__ float sm2[256];
    const int tid = threadIdx.x;
    const int j   = blockIdx.x;            // 0..15, cols [j*64, j*64+64)
    const int col = j * 64 + (tid & 63);
    const int qtr = tid >> 6;              // 4 waves x 16 partial rows each
    float s = 0.0f;
    #pragma unroll
    for (int i = 0; i < 16; i++)
        s += ws[CPART_OFF + (qtr * 16 + i) * 1024 + col];
    sm2[tid] = s;
    __syncthreads();
    if (tid < 64)
        ws[COLSUM_OFF + col] = sm2[tid] + sm2[tid + 64]
                             + sm2[tid + 128] + sm2[tid + 192];
    if (j == 0 && tid < 4) ws[tid] = 0.0f;  // mr, counter, ms, bce
}

// -------- k2: BCE (fp32-exact) + pred->fp8 convert (k-interleaved) + EXACT
// fp32 rowsum via colsum dot -> ms, all on the single streaming read of pred.
// Block bi handles rows bi*8 .. bi*8+7; 32 lanes per row, 8 float4 per lane.
__global__ __launch_bounds__(256)
void bce_rowsum_kernel(const float* __restrict__ pred,
                       const float* __restrict__ membership,
                       const int*   __restrict__ tidx,
                       float*       __restrict__ ws,
                       int*         __restrict__ pred_f8) {
    __shared__ float cs[NSETS];
    __shared__ float sm[4];
    const int tid = threadIdx.x;
    const int bi  = blockIdx.x;

    // stage full colsum (4 KB) into LDS; prev-dispatch data, plain loads OK
    ((float4*)cs)[tid] = ((const float4*)(ws + COLSUM_OFF))[tid];
    __syncthreads();

    const int row = bi * 8 + (tid >> 5);
    const int l   = tid & 31;
    const int cls = tidx[row];             // uniform per half-wave row group
    const float eps = 1e-7f;
    const float hi  = 1.0f - 1e-7f;
    const float4* prow = (const float4*)pred + (size_t)row * 256;
    const float4* mrow = (const float4*)membership + ((size_t)cls << 8);
    const int rbase = row << 8;

    float bacc = 0.0f;                     // BCE log-sum partial
    float rs   = 0.0f;                     // exact rowsum partial
    #pragma unroll
    for (int jj = 0; jj < 8; jj++) {
        const int c4 = l + jj * 32;        // float4 column in row
        const float4 p4 = prow[c4];
        const float4 t4 = mrow[c4];
        const float4 cv = ((const float4*)cs)[c4];
        float cp[4];
        cp[0] = fminf(fmaxf(p4.x, eps), hi);
        cp[1] = fminf(fmaxf(p4.y, eps), hi);
        cp[2] = fminf(fmaxf(p4.z, eps), hi);
        cp[3] = fminf(fmaxf(p4.w, eps), hi);
        pred_f8[rbase | permute_dword(c4)] =
            pk_fp8x4(cp[0], cp[1], cp[2], cp[3]);
        rs += cp[0] * cv.x + cp[1] * cv.y + cp[2] * cv.z + cp[3] * cv.w;
        const float ts[4] = {t4.x, t4.y, t4.z, t4.w};
        #pragma unroll
        for (int u = 0; u < 4; u++) {
            const float x = (ts[u] > 0.5f) ? cp[u] : (1.0f - cp[u]);
            bacc += __logf(x);
        }
    }

    // rowsum reduce within each 32-lane row group; lane l==0 holds the total
    // (tree only needs lanes [0, off) valid at each step, which stay in-group)
    #pragma unroll
    for (int off = 16; off > 0; off >>= 1) rs += __shfl_down(rs, off, 64);
    const float msacc = (l == 0) ? fabsf(rs - 1.0f) : 0.0f;

    const float bsum = block_reduce_sum(bacc, sm);
    if (tid == 0) atomicAdd(&ws[3], bsum);
    __syncthreads();                       // sm reuse guard
    const float msum = block_reduce_sum(msacc, sm);
    if (tid == 0) atomicAdd(&ws[2], msum);
}

// -------- k3: masses = p_fp8 @ moeb_fp8^T via MFMA for mr ONLY.
// Double-buffered LDS, loads issued after the barrier (in flight across the
// MFMA phase); XCD swizzle for A-panel L2 reuse; one-atomic epilogue +
// fence-free global-last finalize.
__global__ __launch_bounds__(256)
void masses_mfma_kernel(const unsigned char* __restrict__ A,   // pred_fp8
                        const unsigned char* __restrict__ Bm,  // moeb_fp8
                        float* __restrict__ ws,
                        float* __restrict__ out) {
    __shared__ __align__(16) unsigned char Alds[2][BM * BK];  // 2 x 16 KB
    __shared__ __align__(16) unsigned char Blds[2][BN * BK];  // 2 x 16 KB
    __shared__ float sm[4];

    const int tid  = threadIdx.x;
    const int lane = tid & 63;
    const int w    = tid >> 6;
    const int wm   = w >> 1;
    const int wn   = w & 1;
    const int lr   = lane & 15;
    const int q    = lane >> 4;

    // XCD-aware swizzle (performance heuristic only)
    const int id     = blockIdx.x;
    const int xcd    = id & 7;
    const int slot   = id >> 3;                 // 0..127 within XCD
    const int grp    = slot >> 3;               // 0..15
    const int stripe = xcd * 16 + grp;
    const int nblk   = slot & 7;
    const int m0     = stripe * BM;
    const int n0     = nblk * BN;

    f32x4 acc[4][4];
    #pragma unroll
    for (int i = 0; i < 4; i++)
        #pragma unroll
        for (int j = 0; j < 4; j++) acc[i][j] = (f32x4){0.f, 0.f, 0.f, 0.f};

    // staging: 1024 slots of 16B per 16KB tile; thread t covers slots
    // s = t + j*256; slot s -> row r = s>>3, 16B-chunk c = s&7 holds global
    // chunk c ^ (r&7)  (fp8 row = 128 B = BK)
    size_t aoff[4], boff[4];
    unsigned loff[4];
    #pragma unroll
    for (int j = 0; j < 4; j++) {
        const int s  = tid + j * 256;
        const int r  = s >> 3;
        const int gc = (s & 7) ^ (r & 7);
        aoff[j] = (size_t)(m0 + r) * NSETS + gc * 16;
        boff[j] = (size_t)(n0 + r) * NSETS + gc * 16;
        loff[j] = (unsigned)(s * 16);
    }
    const int sw = lr & 7;  // fragment-read swizzle term

    // prologue: issue stage of tile 0 into buffer 0
    #pragma unroll
    for (int j = 0; j < 4; j++) {
        gld16(A  + aoff[j], &Alds[0][loff[j]]);
        gld16(Bm + boff[j], &Blds[0][loff[j]]);
    }

    for (int it = 0; it < KITER; it++) {
        const int cur = it & 1;
        __syncthreads();   // drains vmcnt -> buf[cur] ready; WAR-safe for nxt
        if (it + 1 < KITER) {   // issue next tile: in flight during the MFMAs
            const int nk = (it + 1) * BK;
            #pragma unroll
            for (int j = 0; j < 4; j++) {
                gld16(A  + aoff[j] + nk, &Alds[cur ^ 1][loff[j]]);
                gld16(Bm + boff[j] + nk, &Blds[cur ^ 1][loff[j]]);
            }
        }
        // compute on buf[cur]: b128 reads give 2 MFMA k-steps per fragment
        #pragma unroll
        for (int H = 0; H < 2; H++) {
            const int off = 16 * ((4 * H + q) ^ sw);
            s64x2 a[4], b[4];
            #pragma unroll
            for (int mi = 0; mi < 4; mi++)
                a[mi] = *(const s64x2*)&Alds[cur][(wm * 64 + mi * 16 + lr) * BK + off];
            #pragma unroll
            for (int ni = 0; ni < 4; ni++)
                b[ni] = *(const s64x2*)&Blds[cur][(wn * 64 + ni * 16 + lr) * BK + off];
            #pragma unroll
            for (int mi = 0; mi < 4; mi++)
                #pragma unroll
                for (int ni = 0; ni < 4; ni++) {
                    acc[mi][ni] = __builtin_amdgcn_mfma_f32_16x16x32_fp8_fp8(
                        a[mi][0], b[ni][0], acc[mi][ni], 0, 0, 0);
                    acc[mi][ni] = __builtin_amdgcn_mfma_f32_16x16x32_fp8_fp8(
                        a[mi][1], b[ni][1], acc[mi][ni], 0, 0, 0);
                }
        }
    }

    // ---- mr epilogue: one block-reduce, one atomic ----
    float mrpart = 0.0f;
    #pragma unroll
    for (int mi = 0; mi < 4; mi++)
        #pragma unroll
        for (int ni = 0; ni < 4; ni++)
            #pragma unroll
            for (int r = 0; r < 4; r++)
                mrpart += fmaxf(-acc[mi][ni][r], 0.0f);
    const float mrtot = block_reduce_sum(mrpart, sm);  // has a barrier inside
    if (tid == 0) atomicAdd(&ws[0], mrtot);            // device-scope atomic
    __syncthreads();   // drains vmcnt -> mr atomic at coherent point

    // ---- global-last finalize (fence-free counter protocol) ----
    if (tid == 0) {
        const unsigned c = __hip_atomic_fetch_add((unsigned int*)&ws[1], 1u,
                __ATOMIC_RELAXED, __HIP_MEMORY_SCOPE_AGENT);
        if (c == GEMM_BLOCKS - 1) {
            const float inv = 1.0f / ((float)BATCH * (float)NSETS);
            const float bce = -coh_load(ws + 3) * inv;   // prev dispatch
            const float mr  =  coh_load(ws + 0) * inv;   // this dispatch
            const float ms  =  coh_load(ws + 2) / (float)BATCH;
            out[0] = bce + ALPHA * mr + BETA * ms;
            out[1] = bce;
            out[2] = mr;
            out[3] = ms;
        }
    }
}

extern "C" void kernel_launch(void* const* d_in, const int* in_sizes, int n_in,
                              void* d_out, int out_size, void* d_ws, size_t ws_size,
                              hipStream_t stream) {
    const float* pred       = (const float*)d_in[0];
    const float* membership = (const float*)d_in[1];
    const float* moebius    = (const float*)d_in[2];
    const int*   tidx       = (const int*)d_in[3];
    float* out = (float*)d_out;
    float* ws  = (float*)d_ws;
    int* pred_f8 = (int*)((char*)d_ws + WS_PREDF8_OFF);
    int* moeb_f8 = (int*)((char*)d_ws + WS_MOEBF8_OFF);

    moeb_convert_kernel<<<64, 256, 0, stream>>>(moebius, ws, moeb_f8);
    colsum_reduce_kernel<<<16, 256, 0, stream>>>(ws);
    bce_rowsum_kernel<<<2048, 256, 0, stream>>>(pred, membership, tidx, ws, pred_f8);
    masses_mfma_kernel<<<GEMM_BLOCKS, 256, 0, stream>>>(
        (const unsigned char*)pred_f8, (const unsigned char*)moeb_f8, ws, out);
}

// Round 2
// 156.011 us; speedup vs baseline: 1.2140x; 1.2140x over previous
//
#include <hip/hip_runtime.h>
#include <math.h>

#define BATCH 16384
#define NSETS 1024
#define ALPHA 0.001f
#define BETA  0.001f

// R12: two dispatches (R10's proven structure) + R11's colsum insight.
//   k1: BCE (fp32-exact, MLP-restructured) + pred->fp8 + moeb->fp8 + cpart
//   k2: 128 rowsum blocks (exact fp32 ms via p_clip . colsum, PARALLEL with
//       the GEMM, replacing R10's per-GEMM-block A32 epilogue) + 1024 pure
//       fp8 MFMA GEMM blocks (mr) + counter-protocol finalize.
#define BM 128
#define BN 128
#define BK 128
#define NSTRIPE (BATCH / BM)            // 128 m-stripes
#define NBLK_N  (NSETS / BN)            // 8 n-blocks per stripe
#define GEMM_BLOCKS (NSTRIPE * NBLK_N)  // 1024
#define RS_BLOCKS 128                   // rowsum blocks, 128 rows each
#define K2_GRID (GEMM_BLOCKS + RS_BLOCKS)  // 1152
#define KITER (NSETS / BK)              // 8

typedef __attribute__((ext_vector_type(4))) float f32x4;
typedef __attribute__((ext_vector_type(2))) long s64x2;

// ws float-index layout:
//   [0] mr_sum  [1] global counter (uint)  [2] ms_sum  [3] pad
//       (zeroed by k1 block 0; consumed only by k2 -> dispatch-ordered)
//   [4 .. 4+2048)           bce per-block partials (write-once)
//   [4096 .. 4096+65536)    c_part[64][1024] moebius colsum partials (w-once)
// ws byte layout:
//   [393216 ..)              pred_fp8 (16.8 MB, k-interleaved)
//   [393216 + 16777216 ..)   moeb_fp8 (1 MB, k-interleaved)
#define BCEP_OFF   4
#define CPART_OFF  4096
#define WS_PREDF8_OFF 393216
#define WS_MOEBF8_OFF (393216 + BATCH * NSETS)

__device__ __forceinline__ void gld16(const void* g, void* l) {
    __builtin_amdgcn_global_load_lds(
        (const __attribute__((address_space(1))) unsigned int*)g,
        (__attribute__((address_space(3))) unsigned int*)l, 16, 0, 0);
}

// 4 fp32 -> 4 fp8 e4m3 (OCP) packed in an int, HW converter
__device__ __forceinline__ int pk_fp8x4(float a, float b, float c, float d) {
    int v = 0;
    v = __builtin_amdgcn_cvt_pk_fp8_f32(a, b, v, 0);   // low word
    v = __builtin_amdgcn_cvt_pk_fp8_f32(c, d, v, 1);   // high word
    return v;
}

// dword-in-row permutation implementing the 8B k-chunk interleave within each
// 128B k-group: chunk o -> (o&8) | ((o&3)<<1) | ((o>>2)&1).  With this layout
// a lane's MFMA chunks (8H+q, 8H+q+4) are ADJACENT -> b128 fragment reads.
__device__ __forceinline__ int permute_dword(int d) {
    const int g = d >> 5;          // 128B group (32 dwords)
    const int w = d & 31;
    const int o = w >> 1;          // 8B chunk 0..15
    const int p = w & 1;
    const int n = (o & 8) | ((o & 3) << 1) | ((o >> 2) & 1);
    return (g << 5) | (n << 1) | p;
}

// relaxed agent-scope load: bypasses (possibly stale) L1/L2, no cache inval
__device__ __forceinline__ float coh_load(const float* p) {
    return __hip_atomic_load(p, __ATOMIC_RELAXED, __HIP_MEMORY_SCOPE_AGENT);
}

__device__ __forceinline__ float block_reduce_sum(float v, float* sm) {
    #pragma unroll
    for (int off = 32; off > 0; off >>= 1) v += __shfl_down(v, off, 64);
    const int lane = threadIdx.x & 63;
    const int wid  = threadIdx.x >> 6;
    if (lane == 0) sm[wid] = v;
    __syncthreads();
    const int nw = blockDim.x >> 6;
    v = (threadIdx.x < nw) ? sm[threadIdx.x] : 0.0f;
    if (wid == 0) {
        #pragma unroll
        for (int off = 32; off > 0; off >>= 1) v += __shfl_down(v, off, 64);
    }
    return v;  // valid in thread 0
}

// -------- k1: BCE (fp32-exact) + pred->fp8 (k-interleaved); blocks >= 2048
// convert moebius->fp8 and emit write-once colsum partials.
// MLP restructure: block bi covers rows {bi + k*2048}; per 4-row group all
// 8 float4 loads are issued before any compute (defeats the VGPR-minimizing
// serial schedule R11 fell into, VGPR 32 -> ~64).
__global__ __launch_bounds__(256)
void bce_convert_kernel(const float* __restrict__ pred,
                        const float* __restrict__ membership,
                        const int*   __restrict__ tidx,
                        const float* __restrict__ moeb,
                        float*       __restrict__ ws,
                        int*         __restrict__ pred_f8,
                        int*         __restrict__ moeb_f8) {
    const int tid = threadIdx.x;
    const int bi  = blockIdx.x;
    if (bi >= 2048) {   // moebius: 64 blocks; block j handles rows j*16..+15
        const int j    = bi - 2048;
        const int base = j * 4096 + tid;
        float4 csum = make_float4(0.f, 0.f, 0.f, 0.f);
        #pragma unroll
        for (int k = 0; k < 16; k++) {
            const int i = base + k * 256;        // row j*16+k, col4 = tid
            const float4 v = ((const float4*)moeb)[i];
            const int row = i >> 8;
            moeb_f8[(row << 8) | permute_dword(i & 255)] =
                pk_fp8x4(v.x, v.y, v.z, v.w);
            csum.x += v.x; csum.y += v.y; csum.z += v.z; csum.w += v.w;
        }
        ((float4*)(ws + CPART_OFF))[j * 256 + tid] = csum;  // write-once
        return;
    }
    if (bi == 0 && tid < 4) ws[tid] = 0.0f;   // mr, counter, ms, pad

    __shared__ float sm[4];
    const float eps = 1e-7f;
    const float hi  = 1.0f - 1e-7f;
    const int   pd  = permute_dword(tid);     // hoisted: same for all rows
    float acc = 0.0f;
    #pragma unroll
    for (int g = 0; g < 2; g++) {
        float4 P[4], T[4];
        int rows[4];
        // issue all 4 pred loads
        #pragma unroll
        for (int k = 0; k < 4; k++) {
            rows[k] = bi + (g * 4 + k) * 2048;
            P[k] = ((const float4*)pred)[rows[k] * 256 + tid];
        }
        // issue all 4 membership gathers (cls is block-uniform -> s_load)
        #pragma unroll
        for (int k = 0; k < 4; k++) {
            const int cls = tidx[rows[k]];
            T[k] = ((const float4*)membership)[(cls << 8) + tid];
        }
        // compute + fp8 store
        #pragma unroll
        for (int k = 0; k < 4; k++) {
            float cp[4];
            cp[0] = fminf(fmaxf(P[k].x, eps), hi);
            cp[1] = fminf(fmaxf(P[k].y, eps), hi);
            cp[2] = fminf(fmaxf(P[k].z, eps), hi);
            cp[3] = fminf(fmaxf(P[k].w, eps), hi);
            pred_f8[(rows[k] << 8) | pd] = pk_fp8x4(cp[0], cp[1], cp[2], cp[3]);
            const float ts[4] = {T[k].x, T[k].y, T[k].z, T[k].w};
            #pragma unroll
            for (int u = 0; u < 4; u++) {
                const float x = (ts[u] > 0.5f) ? cp[u] : (1.0f - cp[u]);
                acc += __logf(x);
            }
        }
    }
    const float tot = block_reduce_sum(acc, sm);
    if (tid == 0) ws[BCEP_OFF + bi] = tot;    // write-once partial
}

// -------- k2: blocks 0..127 = exact fp32 rowsum/ms (parallel with GEMM);
// blocks 128..1151 = pure fp8 MFMA GEMM (mr). Counter-protocol finalize.
__global__ __launch_bounds__(256)
void masses_mfma_kernel(const unsigned char* __restrict__ A,   // pred_fp8
                        const unsigned char* __restrict__ Bm,  // moeb_fp8
                        const float* __restrict__ pred,        // fp32 (ms)
                        float* __restrict__ ws,
                        float* __restrict__ out) {
    __shared__ __align__(16) unsigned char Alds[2][BM * BK];  // 2 x 16 KB
    __shared__ __align__(16) unsigned char Blds[2][BN * BK];  // 2 x 16 KB
    __shared__ float sm[4];
    __shared__ unsigned flag;

    const int tid = threadIdx.x;
    const int id  = blockIdx.x;

    if (id < RS_BLOCKS) {
        // ---- exact fp32 rowsum: rows [id*128, id*128+128) ----
        float* csl = (float*)Alds;     // colsum[1024] staged in LDS
        {
            const float4* cp4 = (const float4*)(ws + CPART_OFF);  // prev disp.
            float4 c = make_float4(0.f, 0.f, 0.f, 0.f);
            #pragma unroll
            for (int r = 0; r < 64; r++) {
                const float4 v = cp4[r * 256 + tid];
                c.x += v.x; c.y += v.y; c.z += v.z; c.w += v.w;
            }
            ((float4*)csl)[tid] = c;
        }
        __syncthreads();
        const int l   = tid & 31;      // lane within row group
        const int sub = tid >> 5;      // 8 rows per pass
        const float eps = 1e-7f;
        const float hi  = 1.0f - 1e-7f;
        float msacc = 0.0f;
        for (int pass = 0; pass < 16; pass++) {
            const int row = id * 128 + pass * 8 + sub;
            const float4* prow = (const float4*)pred + (size_t)row * 256;
            float rs = 0.0f;
            #pragma unroll
            for (int s = 0; s < 8; s++) {
                const int c4 = l + s * 32;
                float4 p = prow[c4];
                const float4 cv = ((const float4*)csl)[c4];
                p.x = fminf(fmaxf(p.x, eps), hi);
                p.y = fminf(fmaxf(p.y, eps), hi);
                p.z = fminf(fmaxf(p.z, eps), hi);
                p.w = fminf(fmaxf(p.w, eps), hi);
                rs += p.x * cv.x + p.y * cv.y + p.z * cv.z + p.w * cv.w;
            }
            #pragma unroll
            for (int off = 16; off > 0; off >>= 1)
                rs += __shfl_down(rs, off, 32);   // within 32-lane segment
            if (l == 0) msacc += fabsf(rs - 1.0f);
        }
        const float mssum = block_reduce_sum(msacc, sm);
        if (tid == 0) atomicAdd(&ws[2], mssum);
    } else {
        // ---- fp8 MFMA GEMM for mr ----
        const int gid  = id - RS_BLOCKS;
        const int lane = tid & 63;
        const int w    = tid >> 6;
        const int wm   = w >> 1;
        const int wn   = w & 1;
        const int lr   = lane & 15;
        const int q    = lane >> 4;

        // XCD-aware swizzle (id = gid + 128, 128 % 8 == 0 -> mapping intact)
        const int xcd    = gid & 7;
        const int slot   = gid >> 3;                 // 0..127 within XCD
        const int grp    = slot >> 3;                // 0..15
        const int stripe = xcd * 16 + grp;
        const int nblk   = slot & 7;
        const int m0     = stripe * BM;
        const int n0     = nblk * BN;

        f32x4 acc[4][4];
        #pragma unroll
        for (int i = 0; i < 4; i++)
            #pragma unroll
            for (int j = 0; j < 4; j++) acc[i][j] = (f32x4){0.f, 0.f, 0.f, 0.f};

        // staging: 1024 slots of 16B per 16KB tile; thread t covers slots
        // s = t + j*256; slot s -> row r = s>>3, 16B-chunk c = s&7 holds
        // global chunk c ^ (r&7)  (fp8 row = 128 B = BK)
        size_t aoff[4], boff[4];
        unsigned loff[4];
        #pragma unroll
        for (int j = 0; j < 4; j++) {
            const int s  = tid + j * 256;
            const int r  = s >> 3;
            const int gc = (s & 7) ^ (r & 7);
            aoff[j] = (size_t)(m0 + r) * NSETS + gc * 16;
            boff[j] = (size_t)(n0 + r) * NSETS + gc * 16;
            loff[j] = (unsigned)(s * 16);
        }
        const int sw = lr & 7;  // fragment-read swizzle term

        // prologue: issue stage of tile 0 into buffer 0
        #pragma unroll
        for (int j = 0; j < 4; j++) {
            gld16(A  + aoff[j], &Alds[0][loff[j]]);
            gld16(Bm + boff[j], &Blds[0][loff[j]]);
        }

        for (int it = 0; it < KITER; it++) {
            const int cur = it & 1;
            __syncthreads();   // drains vmcnt -> buf[cur] ready; WAR-safe
            if (it + 1 < KITER) {  // next tile in flight during the MFMAs
                const int nk = (it + 1) * BK;
                #pragma unroll
                for (int j = 0; j < 4; j++) {
                    gld16(A  + aoff[j] + nk, &Alds[cur ^ 1][loff[j]]);
                    gld16(Bm + boff[j] + nk, &Blds[cur ^ 1][loff[j]]);
                }
            }
            // compute on buf[cur]: b128 reads give 2 MFMA k-steps/fragment
            #pragma unroll
            for (int H = 0; H < 2; H++) {
                const int off = 16 * ((4 * H + q) ^ sw);
                s64x2 a[4], b[4];
                #pragma unroll
                for (int mi = 0; mi < 4; mi++)
                    a[mi] = *(const s64x2*)
                        &Alds[cur][(wm * 64 + mi * 16 + lr) * BK + off];
                #pragma unroll
                for (int ni = 0; ni < 4; ni++)
                    b[ni] = *(const s64x2*)
                        &Blds[cur][(wn * 64 + ni * 16 + lr) * BK + off];
                #pragma unroll
                for (int mi = 0; mi < 4; mi++)
                    #pragma unroll
                    for (int ni = 0; ni < 4; ni++) {
                        acc[mi][ni] = __builtin_amdgcn_mfma_f32_16x16x32_fp8_fp8(
                            a[mi][0], b[ni][0], acc[mi][ni], 0, 0, 0);
                        acc[mi][ni] = __builtin_amdgcn_mfma_f32_16x16x32_fp8_fp8(
                            a[mi][1], b[ni][1], acc[mi][ni], 0, 0, 0);
                    }
            }
        }

        // mr epilogue: one block-reduce, one atomic
        float mrpart = 0.0f;
        #pragma unroll
        for (int mi = 0; mi < 4; mi++)
            #pragma unroll
            for (int ni = 0; ni < 4; ni++)
                #pragma unroll
                for (int r = 0; r < 4; r++)
                    mrpart += fmaxf(-acc[mi][ni][r], 0.0f);
        const float mrtot = block_reduce_sum(mrpart, sm);
        if (tid == 0) atomicAdd(&ws[0], mrtot);
    }

    // ---- common tail: counter protocol + finalize ----
    __syncthreads();   // drains each wave's vmcnt -> atomics at coherent point
    if (tid == 0)
        flag = (__hip_atomic_fetch_add((unsigned int*)&ws[1], 1u,
                    __ATOMIC_RELAXED, __HIP_MEMORY_SCOPE_AGENT)
                == K2_GRID - 1);
    __syncthreads();
    if (flag) {
        float s_bce = 0.0f;
        #pragma unroll
        for (int k = 0; k < 2; k++) {    // prev-dispatch data: plain loads OK
            const float4 v = ((const float4*)(ws + BCEP_OFF))[tid + k * 256];
            s_bce += v.x + v.y + v.z + v.w;
        }
        const float bcesum = block_reduce_sum(s_bce, sm);
        if (tid == 0) {
            const float inv = 1.0f / ((float)BATCH * (float)NSETS);
            const float bce = -bcesum * inv;
            const float mr  =  coh_load(ws + 0) * inv;
            const float ms  =  coh_load(ws + 2) / (float)BATCH;
            out[0] = bce + ALPHA * mr + BETA * ms;
            out[1] = bce;
            out[2] = mr;
            out[3] = ms;
        }
    }
}

extern "C" void kernel_launch(void* const* d_in, const int* in_sizes, int n_in,
                              void* d_out, int out_size, void* d_ws, size_t ws_size,
                              hipStream_t stream) {
    const float* pred       = (const float*)d_in[0];
    const float* membership = (const float*)d_in[1];
    const float* moebius    = (const float*)d_in[2];
    const int*   tidx       = (const int*)d_in[3];
    float* out = (float*)d_out;
    float* ws  = (float*)d_ws;
    int* pred_f8 = (int*)((char*)d_ws + WS_PREDF8_OFF);
    int* moeb_f8 = (int*)((char*)d_ws + WS_MOEBF8_OFF);

    bce_convert_kernel<<<2048 + 64, 256, 0, stream>>>(
        pred, membership, tidx, moebius, ws, pred_f8, moeb_f8);
    masses_mfma_kernel<<<K2_GRID, 256, 0, stream>>>(
        (const unsigned char*)pred_f8, (const unsigned char*)moeb_f8,
        pred, ws, out);
}

// Round 3
// 151.085 us; speedup vs baseline: 1.2535x; 1.0326x over previous
//
#include <hip/hip_runtime.h>
#include <math.h>

#define BATCH 16384
#define NSETS 1024
#define ALPHA 0.001f
#define BETA  0.001f

// R13 = measured-best hybrid: R12's MLP-batched BCE kernel (loads hoisted,
// ~16 us faster than R10's) + R10's PROVEN masses kernel (51 us: GEMM with
// inline per-block rowsum epilogue over its [n0,n0+128) column chunk --
// load-balanced across all 1024 blocks, overlapped with MFMA).
// R12's separated rowsum blocks regressed (72 us): 128 long skinny blocks
// unbalanced the dispatch and inflated VGPR for all blocks (100->148).
#define BM 128
#define BN 128
#define BK 128
#define NSTRIPE (BATCH / BM)            // 128 m-stripes
#define NBLK_N  (NSETS / BN)            // 8 n-blocks per stripe
#define GEMM_BLOCKS (NSTRIPE * NBLK_N)  // 1024
#define KITER (NSETS / BK)              // 8

typedef __attribute__((ext_vector_type(4))) float f32x4;
typedef __attribute__((ext_vector_type(2))) long s64x2;

// ws float-index layout (R10 layout):
//   [0] mr_sum  [1] global counter (uint)  [2] ms_sum  [3] pad   (zeroed k1 b0)
//   [4 .. 4+2048)            bce per-block partials (write-once)
//   [4096 .. 4096+16384)     row sums (atomics; zeroed by k1 blocks 0..2047)
//   [20480 .. 20480+128)     per-stripe counters (uint; zeroed by k1 block 1)
//   [24576 .. 24576+65536)   c_part[64][1024] moebius colsum partials (w-once)
// ws byte layout:
//   [393216 ..)              pred_fp8 (16.8 MB, k-interleaved)
//   [393216 + 16777216 ..)   moeb_fp8 (1 MB, k-interleaved)
#define BCEP_OFF   4
#define ROWSUM_OFF 4096
#define STRIPE_OFF 20480
#define CPART_OFF  24576
#define WS_PREDF8_OFF 393216
#define WS_MOEBF8_OFF (393216 + BATCH * NSETS)

__device__ __forceinline__ void gld16(const void* g, void* l) {
    __builtin_amdgcn_global_load_lds(
        (const __attribute__((address_space(1))) unsigned int*)g,
        (__attribute__((address_space(3))) unsigned int*)l, 16, 0, 0);
}

// 4 fp32 -> 4 fp8 e4m3 (OCP) packed in an int, HW converter
__device__ __forceinline__ int pk_fp8x4(float a, float b, float c, float d) {
    int v = 0;
    v = __builtin_amdgcn_cvt_pk_fp8_f32(a, b, v, 0);   // low word
    v = __builtin_amdgcn_cvt_pk_fp8_f32(c, d, v, 1);   // high word
    return v;
}

// dword-in-row permutation implementing the 8B k-chunk interleave within each
// 128B k-group: chunk o -> (o&8) | ((o&3)<<1) | ((o>>2)&1).  With this layout
// a lane's MFMA chunks (8H+q, 8H+q+4) are ADJACENT -> b128 fragment reads.
__device__ __forceinline__ int permute_dword(int d) {
    const int g = d >> 5;          // 128B group (32 dwords)
    const int w = d & 31;
    const int o = w >> 1;          // 8B chunk 0..15
    const int p = w & 1;
    const int n = (o & 8) | ((o & 3) << 1) | ((o >> 2) & 1);
    return (g << 5) | (n << 1) | p;
}

// relaxed agent-scope load: bypasses (possibly stale) L1/L2, no cache inval
__device__ __forceinline__ float coh_load(const float* p) {
    return __hip_atomic_load(p, __ATOMIC_RELAXED, __HIP_MEMORY_SCOPE_AGENT);
}

__device__ __forceinline__ float block_reduce_sum(float v, float* sm) {
    #pragma unroll
    for (int off = 32; off > 0; off >>= 1) v += __shfl_down(v, off, 64);
    const int lane = threadIdx.x & 63;
    const int wid  = threadIdx.x >> 6;
    if (lane == 0) sm[wid] = v;
    __syncthreads();
    const int nw = blockDim.x >> 6;
    v = (threadIdx.x < nw) ? sm[threadIdx.x] : 0.0f;
    if (wid == 0) {
        #pragma unroll
        for (int off = 32; off > 0; off >>= 1) v += __shfl_down(v, off, 64);
    }
    return v;  // valid in thread 0
}

// -------- k1: BCE (fp32-exact) + pred->fp8 (k-interleaved) + ws zeroing;
// blocks >= 2048 convert moebius->fp8 and emit write-once colsum partials.
// MLP restructure (R12): block bi covers rows {bi + k*2048}; per 4-row group
// all 8 float4 loads are issued before any compute (defeats the VGPR-
// minimizing serial schedule, VGPR 32 -> ~64).
__global__ __launch_bounds__(256)
void bce_convert_kernel(const float* __restrict__ pred,
                        const float* __restrict__ membership,
                        const int*   __restrict__ tidx,
                        const float* __restrict__ moeb,
                        float*       __restrict__ ws,
                        int*         __restrict__ pred_f8,
                        int*         __restrict__ moeb_f8) {
    const int tid = threadIdx.x;
    const int bi  = blockIdx.x;
    if (bi >= 2048) {   // moebius: 64 blocks; block j handles rows j*16..+15
        const int j    = bi - 2048;
        const int base = j * 4096 + tid;
        float4 csum = make_float4(0.f, 0.f, 0.f, 0.f);
        #pragma unroll
        for (int k = 0; k < 16; k++) {
            const int i = base + k * 256;        // row j*16+k, col4 = tid
            const float4 v = ((const float4*)moeb)[i];
            const int row = i >> 8;
            moeb_f8[(row << 8) | permute_dword(i & 255)] =
                pk_fp8x4(v.x, v.y, v.z, v.w);
            csum.x += v.x; csum.y += v.y; csum.z += v.z; csum.w += v.w;
        }
        ((float4*)(ws + CPART_OFF))[j * 256 + tid] = csum;  // write-once
        return;
    }
    // zero accumulators for the masses kernel (stream order guarantees vis.)
    if (tid < 8)                    ws[ROWSUM_OFF + bi * 8 + tid] = 0.0f;
    if (bi == 0 && tid >= 8 && tid < 12) ws[tid - 8] = 0.0f;
    if (bi == 1 && tid < NSTRIPE)   ws[STRIPE_OFF + tid] = 0.0f;

    __shared__ float sm[4];
    const float eps = 1e-7f;
    const float hi  = 1.0f - 1e-7f;
    const int   pd  = permute_dword(tid);     // hoisted: same for all rows
    float acc = 0.0f;
    #pragma unroll
    for (int g = 0; g < 2; g++) {
        float4 P[4], T[4];
        int rows[4];
        // issue all 4 pred loads
        #pragma unroll
        for (int k = 0; k < 4; k++) {
            rows[k] = bi + (g * 4 + k) * 2048;
            P[k] = ((const float4*)pred)[rows[k] * 256 + tid];
        }
        // issue all 4 membership gathers (cls is block-uniform -> s_load)
        #pragma unroll
        for (int k = 0; k < 4; k++) {
            const int cls = tidx[rows[k]];
            T[k] = ((const float4*)membership)[(cls << 8) + tid];
        }
        // compute + fp8 store
        #pragma unroll
        for (int k = 0; k < 4; k++) {
            float cp[4];
            cp[0] = fminf(fmaxf(P[k].x, eps), hi);
            cp[1] = fminf(fmaxf(P[k].y, eps), hi);
            cp[2] = fminf(fmaxf(P[k].z, eps), hi);
            cp[3] = fminf(fmaxf(P[k].w, eps), hi);
            pred_f8[(rows[k] << 8) | pd] = pk_fp8x4(cp[0], cp[1], cp[2], cp[3]);
            const float ts[4] = {T[k].x, T[k].y, T[k].z, T[k].w};
            #pragma unroll
            for (int u = 0; u < 4; u++) {
                const float x = (ts[u] > 0.5f) ? cp[u] : (1.0f - cp[u]);
                acc += __logf(x);
            }
        }
    }
    const float tot = block_reduce_sum(acc, sm);
    if (tid == 0) ws[BCEP_OFF + bi] = tot;    // write-once partial
}

// -------- k2 (R10 proven, verbatim): masses = p_fp8 @ moeb_fp8^T via MFMA
// for mr; distributed exact fp32 rowsum partials for ms (inline epilogue,
// 64 KB A32 per block, load-balanced); stripe-last folds; global-last
// finalizes. Double-buffered LDS; fence-free counter protocol; XCD swizzle.
__global__ __launch_bounds__(256)
void masses_mfma_kernel(const unsigned char* __restrict__ A,   // pred_fp8
                        const unsigned char* __restrict__ Bm,  // moeb_fp8
                        const float* __restrict__ A32,         // pred fp32
                        float* __restrict__ ws,
                        float* __restrict__ out) {
    __shared__ __align__(16) unsigned char Alds[2][BM * BK];  // 2 x 16 KB
    __shared__ __align__(16) unsigned char Blds[2][BN * BK];  // 2 x 16 KB
    __shared__ float sm[4];
    __shared__ unsigned flag;

    const int tid  = threadIdx.x;
    const int lane = tid & 63;
    const int w    = tid >> 6;
    const int wm   = w >> 1;
    const int wn   = w & 1;
    const int lr   = lane & 15;
    const int q    = lane >> 4;

    // XCD-aware swizzle (performance heuristic only)
    const int id     = blockIdx.x;
    const int xcd    = id & 7;
    const int slot   = id >> 3;                 // 0..127 within XCD
    const int grp    = slot >> 3;               // 0..15
    const int stripe = xcd * 16 + grp;
    const int nblk   = slot & 7;
    const int m0     = stripe * BM;
    const int n0     = nblk * BN;               // also this block's k-chunk base

    f32x4 acc[4][4];
    #pragma unroll
    for (int i = 0; i < 4; i++)
        #pragma unroll
        for (int j = 0; j < 4; j++) acc[i][j] = (f32x4){0.f, 0.f, 0.f, 0.f};

    // staging: 1024 slots of 16B per 16KB tile; thread t covers slots
    // s = t + j*256; slot s -> row r = s>>3, 16B-chunk c = s&7 holds global
    // chunk c ^ (r&7)  (fp8 row = 128 B = BK)
    size_t aoff[4], boff[4];
    unsigned loff[4];
    #pragma unroll
    for (int j = 0; j < 4; j++) {
        const int s  = tid + j * 256;
        const int r  = s >> 3;
        const int gc = (s & 7) ^ (r & 7);
        aoff[j] = (size_t)(m0 + r) * NSETS + gc * 16;
        boff[j] = (size_t)(n0 + r) * NSETS + gc * 16;
        loff[j] = (unsigned)(s * 16);
    }
    const int sw = lr & 7;  // fragment-read swizzle term

    // prologue: issue stage of tile 0 into buffer 0
    #pragma unroll
    for (int j = 0; j < 4; j++) {
        gld16(A  + aoff[j], &Alds[0][loff[j]]);
        gld16(Bm + boff[j], &Blds[0][loff[j]]);
    }

    for (int it = 0; it < KITER; it++) {
        const int cur = it & 1;
        __syncthreads();   // drains vmcnt -> buf[cur] ready; WAR-safe for nxt
        if (it + 1 < KITER) {   // issue next tile: in flight during the MFMAs
            const int nk = (it + 1) * BK;
            #pragma unroll
            for (int j = 0; j < 4; j++) {
                gld16(A  + aoff[j] + nk, &Alds[cur ^ 1][loff[j]]);
                gld16(Bm + boff[j] + nk, &Blds[cur ^ 1][loff[j]]);
            }
        }
        // compute on buf[cur]: b128 reads give 2 MFMA k-steps per fragment
        #pragma unroll
        for (int H = 0; H < 2; H++) {
            const int off = 16 * ((4 * H + q) ^ sw);
            s64x2 a[4], b[4];
            #pragma unroll
            for (int mi = 0; mi < 4; mi++)
                a[mi] = *(const s64x2*)&Alds[cur][(wm * 64 + mi * 16 + lr) * BK + off];
            #pragma unroll
            for (int ni = 0; ni < 4; ni++)
                b[ni] = *(const s64x2*)&Blds[cur][(wn * 64 + ni * 16 + lr) * BK + off];
            #pragma unroll
            for (int mi = 0; mi < 4; mi++)
                #pragma unroll
                for (int ni = 0; ni < 4; ni++) {
                    acc[mi][ni] = __builtin_amdgcn_mfma_f32_16x16x32_fp8_fp8(
                        a[mi][0], b[ni][0], acc[mi][ni], 0, 0, 0);
                    acc[mi][ni] = __builtin_amdgcn_mfma_f32_16x16x32_fp8_fp8(
                        a[mi][1], b[ni][1], acc[mi][ni], 0, 0, 0);
                }
        }
    }

    // ---- mr epilogue ----
    float mrpart = 0.0f;
    #pragma unroll
    for (int mi = 0; mi < 4; mi++)
        #pragma unroll
        for (int ni = 0; ni < 4; ni++)
            #pragma unroll
            for (int r = 0; r < 4; r++)
                mrpart += fmaxf(-acc[mi][ni][r], 0.0f);
    const float mrtot = block_reduce_sum(mrpart, sm);  // has a barrier inside
    if (tid == 0) atomicAdd(&ws[0], mrtot);            // device-scope atomic

    // ---- distributed exact fp32 rowsum partial: k-chunk [n0, n0+128) ----
    __syncthreads();                 // all MFMA reads done -> Alds reusable
    float* clds = (float*)Alds;      // [0..1024) seg partials, [1024..1152) c
    {
        const int col = tid & 31;    // f4-col within the 128-float chunk
        const int seg = tid >> 5;    // 8 segments of 8 c_part rows each
        float4 cs = make_float4(0.f, 0.f, 0.f, 0.f);
        #pragma unroll
        for (int j = 0; j < 8; j++) {   // prev-dispatch data: plain loads OK
            const float4 v = ((const float4*)(ws + CPART_OFF))
                                 [(seg * 8 + j) * 256 + (n0 >> 2) + col];
            cs.x += v.x; cs.y += v.y; cs.z += v.z; cs.w += v.w;
        }
        ((float4*)clds)[seg * 32 + col] = cs;
    }
    __syncthreads();
    if (tid < 32) {
        float4 t = make_float4(0.f, 0.f, 0.f, 0.f);
        #pragma unroll
        for (int s2 = 0; s2 < 8; s2++) {
            const float4 v = ((const float4*)clds)[s2 * 32 + tid];
            t.x += v.x; t.y += v.y; t.z += v.z; t.w += v.w;
        }
        ((float4*)clds)[256 + tid] = t;   // final c chunk at floats [1024..)
    }
    __syncthreads();
    {
        const float eps = 1e-7f;
        const float hi  = 1.0f - 1e-7f;
        const int r    = tid >> 1;        // row within stripe
        const int half = tid & 1;         // 64 k each
        const float4* prow = (const float4*)(A32 + (size_t)(m0 + r) * NSETS
                                             + n0 + half * 64);
        const float4* crow = (const float4*)(clds + 1024 + half * 64);
        float s = 0.0f;
        #pragma unroll
        for (int k = 0; k < 16; k++) {
            float4 pv = prow[k];
            const float4 cv = crow[k];
            pv.x = fminf(fmaxf(pv.x, eps), hi);
            pv.y = fminf(fmaxf(pv.y, eps), hi);
            pv.z = fminf(fmaxf(pv.z, eps), hi);
            pv.w = fminf(fmaxf(pv.w, eps), hi);
            s += pv.x * cv.x + pv.y * cv.y + pv.z * cv.z + pv.w * cv.w;
        }
        s += __shfl_xor(s, 1, 64);        // combine the two k-halves
        if (half == 0) atomicAdd(&ws[ROWSUM_OFF + m0 + r], s);
    }

    // ---- stripe-last: fold |rowsum-1| (fence-free counter protocol) ----
    __syncthreads();   // drains each wave's vmcnt -> atomics at coherent point
    if (tid == 0)
        flag = (__hip_atomic_fetch_add((unsigned int*)&ws[STRIPE_OFF + stripe],
                    1u, __ATOMIC_RELAXED, __HIP_MEMORY_SCOPE_AGENT)
                == NBLK_N - 1);
    __syncthreads();
    if (flag) {
        float sms = 0.0f;
        if (tid < BM)
            sms = fabsf(coh_load(ws + ROWSUM_OFF + m0 + tid) - 1.0f);
        __syncthreads();                 // sm reuse guard
        const float mssum = block_reduce_sum(sms, sm);
        if (tid == 0) atomicAdd(&ws[2], mssum);
    }
    __syncthreads();   // drain the ms atomic before the global bump

    // ---- global-last finalize ----
    if (tid == 0)
        flag = (__hip_atomic_fetch_add((unsigned int*)&ws[1], 1u,
                    __ATOMIC_RELAXED, __HIP_MEMORY_SCOPE_AGENT)
                == GEMM_BLOCKS - 1);
    __syncthreads();
    if (flag) {
        float s_bce = 0.0f;
        #pragma unroll
        for (int k = 0; k < 2; k++) {    // prev-dispatch data: plain loads OK
            const float4 v = ((const float4*)(ws + BCEP_OFF))[tid + k * 256];
            s_bce += v.x + v.y + v.z + v.w;
        }
        __syncthreads();                 // sm reuse guard
        const float bcesum = block_reduce_sum(s_bce, sm);
        if (tid == 0) {
            const float inv = 1.0f / ((float)BATCH * (float)NSETS);
            const float bce = -bcesum * inv;
            const float mr  =  coh_load(ws + 0) * inv;
            const float ms  =  coh_load(ws + 2) / (float)BATCH;
            out[0] = bce + ALPHA * mr + BETA * ms;
            out[1] = bce;
            out[2] = mr;
            out[3] = ms;
        }
    }
}

extern "C" void kernel_launch(void* const* d_in, const int* in_sizes, int n_in,
                              void* d_out, int out_size, void* d_ws, size_t ws_size,
                              hipStream_t stream) {
    const float* pred       = (const float*)d_in[0];
    const float* membership = (const float*)d_in[1];
    const float* moebius    = (const float*)d_in[2];
    const int*   tidx       = (const int*)d_in[3];
    float* out = (float*)d_out;
    float* ws  = (float*)d_ws;
    int* pred_f8 = (int*)((char*)d_ws + WS_PREDF8_OFF);
    int* moeb_f8 = (int*)((char*)d_ws + WS_MOEBF8_OFF);

    bce_convert_kernel<<<2048 + 64, 256, 0, stream>>>(
        pred, membership, tidx, moebius, ws, pred_f8, moeb_f8);
    masses_mfma_kernel<<<GEMM_BLOCKS, 256, 0, stream>>>(
        (const unsigned char*)pred_f8, (const unsigned char*)moeb_f8,
        pred, ws, out);
}